// Round 12
// baseline (529.494 us; speedup 1.0000x reference)
//
#include <hip/hip_runtime.h>
#include <hip/hip_bf16.h>

// Identifier kernel, zero-parameter form (required; parameterized variant
// broke the run in rounds 1-5).
__global__ void UnifiedGNN_56521769616171_kernel() {}

// ---------------- setup: degree count / scan / CSR fill ----------------

__global__ void gnn_zero(int* p, int n) {
  int i = blockIdx.x * 256 + threadIdx.x;
  if (i < n) p[i] = 0;
}

__global__ void gnn_count(const int* dst, int* counts, int e, int n) {
  int i = blockIdx.x * 256 + threadIdx.x;
  if (i < e) {
    int d = dst[i];
    if (d >= 0 && d < n) atomicAdd(&counts[d], 1);
  }
}

__global__ void gnn_scan1(const int* counts, int* row_ptr, int* partials, int n) {
  __shared__ int wsum[4];
  int tid = threadIdx.x;
  int base = blockIdx.x * 1024 + tid * 4;
  int a0 = 0, a1 = 0, a2 = 0, a3 = 0;
  if (base + 3 < n) {
    a0 = counts[base]; a1 = counts[base + 1];
    a2 = counts[base + 2]; a3 = counts[base + 3];
  } else if (base < n) {
    a0 = counts[base];
    if (base + 1 < n) a1 = counts[base + 1];
    if (base + 2 < n) a2 = counts[base + 2];
  }
  int s0 = a0, s1 = s0 + a1, s2 = s1 + a2, s3 = s2 + a3;
  int lane = tid & 63;
  int wv = tid >> 6;
  int incl = s3;
  for (int off = 1; off < 64; off <<= 1) {
    int t = __shfl_up(incl, off);
    if (lane >= off) incl += t;
  }
  if (lane == 63) wsum[wv] = incl;
  __syncthreads();
  int woff = 0;
  for (int j = 0; j < 4; j++)
    if (j < wv) woff += wsum[j];
  int excl = woff + incl - s3;
  if (base < n) {
    row_ptr[base] = excl;
    if (base + 1 < n) row_ptr[base + 1] = excl + s0;
    if (base + 2 < n) row_ptr[base + 2] = excl + s1;
    if (base + 3 < n) row_ptr[base + 3] = excl + s2;
  }
  if (tid == 255) partials[blockIdx.x] = wsum[0] + wsum[1] + wsum[2] + wsum[3];
}

__global__ void gnn_scan2(const int* partials, int* offsets, int nb,
                          int* row_ptr, int n, int etot) {
  int l = threadIdx.x;
  int v = 0;
  if (l < nb) v = partials[l];
  int orig = v;
  for (int off = 1; off < 64; off <<= 1) {
    int t = __shfl_up(v, off);
    if (l >= off) v += t;
  }
  offsets[l] = v - orig;
  if (l == 0) row_ptr[n] = etot;
}

__global__ void gnn_scan3(int* row_ptr, const int* offsets, int* cursor,
                          const int* counts, float* dis, int n) {
  int base = blockIdx.x * 1024 + threadIdx.x * 4;
  int off = offsets[blockIdx.x];
  for (int j = 0; j < 4; j++) {
    int i = base + j;
    if (i < n) {
      int rp = row_ptr[i] + off;
      row_ptr[i] = rp;
      cursor[i] = rp;
      dis[i] = rsqrtf((float)counts[i] + 1.0f);  // degree incl. self-loop
    }
  }
}

__global__ void gnn_fill(const int* src, const int* dst, int* cursor,
                         int* csr, int e, int n) {
  int i = blockIdx.x * 256 + threadIdx.x;
  if (i < e) {
    int d = dst[i];
    if (d >= 0 && d < n) {
      int pos = atomicAdd(&cursor[d], 1);
      csr[pos] = src[i];
    }
  }
}

// ------- GEMM: P[r][c] = sum_k X[r][k] * W[k][c]  (all f32) -------
// 32 rows/block, 256 threads, 4x4 register tile. W staged to LDS in two
// 64-row halves (32 KB each). In-place (X == P) safe: block-private rows
// staged to LDS before any write.

__global__ void gnn_gemm(const float* X, const float* W, float* P, int n,
                         int* live) {
  __shared__ float Xs[128][36];   // X^T tile [k][row], padded
  __shared__ float Ws[64][128];   // W half-tile, f32 (32 KB)
  int tid = threadIdx.x;
  int rowbase = blockIdx.x * 32;
  if (tid == 0 && blockIdx.x == 0) atomicAdd(live, 1);

  for (int i = tid; i < 1024; i += 256) {
    int r = i >> 5;
    int q = i & 31;
    int c = q * 4;
    float4 x4 = make_float4(0.0f, 0.0f, 0.0f, 0.0f);
    int row = rowbase + r;
    if (row < n) x4 = *(const float4*)(X + (size_t)row * 128 + c);
    Xs[c + 0][r] = x4.x;
    Xs[c + 1][r] = x4.y;
    Xs[c + 2][r] = x4.z;
    Xs[c + 3][r] = x4.w;
  }

  int cx = tid & 31;
  int ry = tid >> 5;
  int r0 = ry * 4;
  float acc[4][4];
  for (int a = 0; a < 4; a++)
    for (int b = 0; b < 4; b++) acc[a][b] = 0.0f;

  for (int half = 0; half < 2; half++) {
    __syncthreads();  // Xs staged (half 0) / prior Ws readers done (half 1)
    for (int i = tid; i < 2048; i += 256) {
      int kr = i >> 5;
      int q = i & 31;
      float4 w4 = *(const float4*)(W + (size_t)(half * 64 + kr) * 128 + q * 4);
      *(float4*)&Ws[kr][q * 4] = w4;
    }
    __syncthreads();
    int kb = half * 64;
    for (int k = 0; k < 64; ++k) {
      float x0 = Xs[kb + k][r0 + 0];
      float x1 = Xs[kb + k][r0 + 1];
      float x2 = Xs[kb + k][r0 + 2];
      float x3 = Xs[kb + k][r0 + 3];
      float4 w4 = *(const float4*)&Ws[k][cx * 4];
      acc[0][0] += x0 * w4.x; acc[0][1] += x0 * w4.y; acc[0][2] += x0 * w4.z; acc[0][3] += x0 * w4.w;
      acc[1][0] += x1 * w4.x; acc[1][1] += x1 * w4.y; acc[1][2] += x1 * w4.z; acc[1][3] += x1 * w4.w;
      acc[2][0] += x2 * w4.x; acc[2][1] += x2 * w4.y; acc[2][2] += x2 * w4.z; acc[2][3] += x2 * w4.w;
      acc[3][0] += x3 * w4.x; acc[3][1] += x3 * w4.y; acc[3][2] += x3 * w4.z; acc[3][3] += x3 * w4.w;
    }
  }

  for (int r = 0; r < 4; r++) {
    int row = rowbase + r0 + r;
    if (row < n) {
      float4 o = make_float4(acc[r][0], acc[r][1], acc[r][2], acc[r][3]);
      *(float4*)(P + (size_t)row * 128 + cx * 4) = o;
    }
  }
}

// --- aggregation: out[d] = dis[d]*sum_{s in N(d)} dis[s]*P[s]
//                           + dis[d]^2*P[d] + bias   (all f32) ---

__global__ void gnn_agg(const float* P, const float* dis, const int* row_ptr,
                        const int* csr, const float* bias, float* out, int n,
                        int* live) {
  if (threadIdx.x == 0 && blockIdx.x == 0) atomicAdd(live, 1);
  int row = blockIdx.x * 4 + (threadIdx.x >> 6);
  if (row >= n) return;
  int lane = threadIdx.x & 63;
  int e0 = row_ptr[row];
  int e1 = row_ptr[row + 1];
  const float2* Pv = (const float2*)P;
  float ax = 0.0f, ay = 0.0f;
  for (int e = e0; e < e1; ++e) {
    int s = csr[e];
    if (s < 0 || s >= n) continue;
    float w = dis[s];
    float2 v = Pv[(size_t)s * 64 + lane];
    ax += w * v.x;
    ay += w * v.y;
  }
  float dd = dis[row];
  float2 sv = Pv[(size_t)row * 64 + lane];
  float2 bb = ((const float2*)bias)[lane];
  float ox = dd * ax + dd * dd * sv.x + bb.x;
  float oy = dd * ay + dd * dd * sv.y + bb.y;
  ((float2*)out)[(size_t)row * 64 + lane] = make_float2(ox, oy);
}

// ---------------- P = relu(LayerNorm(Q + ori))  (all f32) ----------------

__global__ void gnn_ln(const float* Q, const float* ori, const float* lw,
                       const float* lb, float* P, int n, int* live) {
  if (threadIdx.x == 0 && blockIdx.x == 0) atomicAdd(live, 1);
  int row = blockIdx.x * 4 + (threadIdx.x >> 6);
  if (row >= n) return;
  int lane = threadIdx.x & 63;
  float2 h2 = ((const float2*)Q)[(size_t)row * 64 + lane];
  float2 o2 = ((const float2*)ori)[(size_t)row * 64 + lane];
  float vx = h2.x + o2.x;
  float vy = h2.y + o2.y;
  float s = vx + vy;
  float sq = vx * vx + vy * vy;
  for (int off = 32; off >= 1; off >>= 1) {
    s += __shfl_xor(s, off);
    sq += __shfl_xor(sq, off);
  }
  float mu = s * (1.0f / 128.0f);
  float var = sq * (1.0f / 128.0f) - mu * mu;
  float inv = rsqrtf(var + 1e-5f);
  float2 w2 = ((const float2*)lw)[lane];
  float2 b2 = ((const float2*)lb)[lane];
  float y0 = (vx - mu) * inv * w2.x + b2.x;
  float y1 = (vy - mu) * inv * w2.y + b2.y;
  if (y0 < 0.0f) y0 = 0.0f;
  if (y1 < 0.0f) y1 = 0.0f;
  ((float2*)P)[(size_t)row * 64 + lane] = make_float2(y0, y1);
}

// Liveness: if any of the 8 pipeline kernels failed to launch, encode count.
__global__ void gnn_live_check(const int* live, float* out) {
  if (threadIdx.x == 0 && blockIdx.x == 0) {
    if (live[0] != 8) out[0] = 1000.0f + 10.0f * (float)live[0];
  }
}

// ---------------- driver ----------------

extern "C" void kernel_launch(void* const* d_in, const int* in_sizes, int n_in,
                              void* d_out, int out_size, void* d_ws, size_t ws_size,
                              hipStream_t stream) {
  UnifiedGNN_56521769616171_kernel<<<1, 64, 0, stream>>>();

  // input classification by size (identity under documented dict order;
  // also handles reference-signature order)
  int nI = (n_in > 0 && n_in <= 16) ? n_in : 11;
  long best = -1;
  int iFeat = 0;
  for (int i = 0; i < nI; i++)
    if ((long)in_sizes[i] > best) { best = in_sizes[i]; iFeat = i; }
  int iW[2], iV[6], iE[2];
  int nW = 0, nV = 0, nE = 0;
  for (int i = 0; i < nI; i++) {
    if (i == iFeat) continue;
    int s = in_sizes[i];
    if (s == 128 * 128) { if (nW < 2) iW[nW++] = i; }
    else if (s == 128)  { if (nV < 6) iV[nV++] = i; }
    else                { if (nE < 2) iE[nE++] = i; }
  }
  int aFeat = 0, aEs = 1, aEd = 2, aW1 = 3, aB1 = 4, aW2 = 5, aB2 = 6,
      aL1w = 7, aL1b = 8, aL2w = 9, aL2b = 10;
  if (nW == 2 && nV == 6 && nE == 2) {
    aFeat = iFeat;
    aEs = iE[0]; aEd = iE[1];
    aW1 = iW[0]; aW2 = iW[1];
    aB1 = iV[0]; aB2 = iV[1];
    aL1w = iV[2]; aL1b = iV[3]; aL2w = iV[4]; aL2b = iV[5];
  }

  int N = 50000;
  int E = 600000;
  if (in_sizes[aFeat] > 0 && (in_sizes[aFeat] % 128) == 0) N = in_sizes[aFeat] / 128;
  if (in_sizes[aEs] > 0) E = in_sizes[aEs];

  const float* in_feat = (const float*)d_in[aFeat];
  const int*   esrc    = (const int*)d_in[aEs];
  const int*   edst    = (const int*)d_in[aEd];
  const float* W1      = (const float*)d_in[aW1];
  const float* b1      = (const float*)d_in[aB1];
  const float* W2      = (const float*)d_in[aW2];
  const float* b2      = (const float*)d_in[aB2];
  const float* ln1w    = (const float*)d_in[aL1w];
  const float* ln1b    = (const float*)d_in[aL1b];
  const float* ln2w    = (const float*)d_in[aL2w];
  const float* ln2b    = (const float*)d_in[aL2b];

  // workspace carve (~28.5 MB total; f32-P branch engaging in R10/11 proved
  // ws_size >= ~31 MB)
  char* base = (char*)d_ws;
  size_t off = 0;
  int* live = (int*)(base + off);       off += 256;
  int* counts = (int*)(base + off);     off += ((size_t)N * 4 + 255) & ~(size_t)255;
  int* row_ptr = (int*)(base + off);    off += ((size_t)(N + 1) * 4 + 255) & ~(size_t)255;
  int* cursor = (int*)(base + off);     off += ((size_t)N * 4 + 255) & ~(size_t)255;
  int* partials = (int*)(base + off);   off += 256;
  int* offsets = (int*)(base + off);    off += 256;
  float* dis = (float*)(base + off);    off += ((size_t)N * 4 + 255) & ~(size_t)255;
  int* csr = (int*)(base + off);        off += ((size_t)E * 4 + 255) & ~(size_t)255;
  float* P = (float*)(base + off);      // N*128 f32 = 25.6 MB

  float* Q = (float*)d_out;  // h buffer (f32, 25.6 MB); overwritten by final agg

  int nb = (N + 1023) / 1024;
  int gN = (N + 255) / 256;
  int gE = (E + 255) / 256;
  int gemm_grid = (N + 31) / 32;
  int row_grid = (N + 3) / 4;

  gnn_zero<<<1, 256, 0, stream>>>(live, 1);
  gnn_zero<<<gN, 256, 0, stream>>>(counts, N);
  gnn_count<<<gE, 256, 0, stream>>>(edst, counts, E, N);
  gnn_scan1<<<nb, 256, 0, stream>>>(counts, row_ptr, partials, N);
  gnn_scan2<<<1, 64, 0, stream>>>(partials, offsets, nb, row_ptr, N, E);
  gnn_scan3<<<nb, 256, 0, stream>>>(row_ptr, offsets, cursor, counts, dis, N);
  gnn_fill<<<gE, 256, 0, stream>>>(esrc, edst, cursor, csr, E, N);

  // conv1: P = in_feat @ W1 ; Q = propagate(P) + b1
  gnn_gemm<<<gemm_grid, 256, 0, stream>>>(in_feat, W1, P, N, live);
  gnn_agg<<<row_grid, 256, 0, stream>>>(P, dis, row_ptr, csr, b1, Q, N, live);

  // iter 0: P = relu(LN1(Q + ori)); P = P @ W2 (in-place); Q = prop(P) + b2
  gnn_ln<<<row_grid, 256, 0, stream>>>(Q, in_feat, ln1w, ln1b, P, N, live);
  gnn_gemm<<<gemm_grid, 256, 0, stream>>>(P, W2, P, N, live);
  gnn_agg<<<row_grid, 256, 0, stream>>>(P, dis, row_ptr, csr, b2, Q, N, live);

  // iter 1: P = relu(LN2(Q + ori)); P = P @ W2 (in-place); d_out = prop(P) + b2
  gnn_ln<<<row_grid, 256, 0, stream>>>(Q, in_feat, ln2w, ln2b, P, N, live);
  gnn_gemm<<<gemm_grid, 256, 0, stream>>>(P, W2, P, N, live);
  gnn_agg<<<row_grid, 256, 0, stream>>>(P, dis, row_ptr, csr, b2, (float*)d_out, N, live);

  gnn_live_check<<<1, 64, 0, stream>>>(live, (float*)d_out);
}

// Round 13
// 371.346 us; speedup vs baseline: 1.4259x; 1.4259x over previous
//
#include <hip/hip_runtime.h>
#include <hip/hip_bf16.h>

typedef unsigned short bf16_t;  // raw bf16 bits

__device__ __forceinline__ float bf2f(bf16_t u) {
  return __uint_as_float(((unsigned int)u) << 16);
}
__device__ __forceinline__ bf16_t f2bf(float f) {
  unsigned int u = __float_as_uint(f);
  return (bf16_t)((u + 0x7FFFu + ((u >> 16) & 1u)) >> 16);  // RNE
}

// Identifier kernel, zero-parameter form (load-bearing: parameterized variant
// broke the harness in rounds 1-5).
__global__ void UnifiedGNN_56521769616171_kernel() {}

// ---------------- setup: degree count / scan / CSR fill ----------------

__global__ void gnn_zero(int* p, int n) {
  int i = blockIdx.x * 256 + threadIdx.x;
  if (i < n) p[i] = 0;
}

__global__ void gnn_count(const int* dst, int* counts, int e, int n) {
  int i = blockIdx.x * 256 + threadIdx.x;
  if (i < e) {
    int d = dst[i];
    if (d >= 0 && d < n) atomicAdd(&counts[d], 1);
  }
}

__global__ void gnn_scan1(const int* counts, int* row_ptr, int* partials, int n) {
  __shared__ int wsum[4];
  int tid = threadIdx.x;
  int base = blockIdx.x * 1024 + tid * 4;
  int a0 = 0, a1 = 0, a2 = 0, a3 = 0;
  if (base + 3 < n) {
    a0 = counts[base]; a1 = counts[base + 1];
    a2 = counts[base + 2]; a3 = counts[base + 3];
  } else if (base < n) {
    a0 = counts[base];
    if (base + 1 < n) a1 = counts[base + 1];
    if (base + 2 < n) a2 = counts[base + 2];
  }
  int s0 = a0, s1 = s0 + a1, s2 = s1 + a2, s3 = s2 + a3;
  int lane = tid & 63;
  int wv = tid >> 6;
  int incl = s3;
  for (int off = 1; off < 64; off <<= 1) {
    int t = __shfl_up(incl, off);
    if (lane >= off) incl += t;
  }
  if (lane == 63) wsum[wv] = incl;
  __syncthreads();
  int woff = 0;
  for (int j = 0; j < 4; j++)
    if (j < wv) woff += wsum[j];
  int excl = woff + incl - s3;
  if (base < n) {
    row_ptr[base] = excl;
    if (base + 1 < n) row_ptr[base + 1] = excl + s0;
    if (base + 2 < n) row_ptr[base + 2] = excl + s1;
    if (base + 3 < n) row_ptr[base + 3] = excl + s2;
  }
  if (tid == 255) partials[blockIdx.x] = wsum[0] + wsum[1] + wsum[2] + wsum[3];
}

__global__ void gnn_scan2(const int* partials, int* offsets, int nb,
                          int* row_ptr, int n, int etot) {
  int l = threadIdx.x;
  int v = 0;
  if (l < nb) v = partials[l];
  int orig = v;
  for (int off = 1; off < 64; off <<= 1) {
    int t = __shfl_up(v, off);
    if (l >= off) v += t;
  }
  offsets[l] = v - orig;
  if (l == 0) row_ptr[n] = etot;
}

__global__ void gnn_scan3(int* row_ptr, const int* offsets, int* cursor,
                          const int* counts, float* dis, int n) {
  int base = blockIdx.x * 1024 + threadIdx.x * 4;
  int off = offsets[blockIdx.x];
  for (int j = 0; j < 4; j++) {
    int i = base + j;
    if (i < n) {
      int rp = row_ptr[i] + off;
      row_ptr[i] = rp;
      cursor[i] = rp;
      dis[i] = rsqrtf((float)counts[i] + 1.0f);  // degree incl. self-loop
    }
  }
}

__global__ void gnn_fill(const int* src, const int* dst, int* cursor,
                         int* csr, int e, int n) {
  int i = blockIdx.x * 256 + threadIdx.x;
  if (i < e) {
    int d = dst[i];
    if (d >= 0 && d < n) {
      int pos = atomicAdd(&cursor[d], 1);
      csr[pos] = src[i];
    }
  }
}

// ------- GEMM: A[r][c] = dis[r] * sum_k X[r][k] * W[k][c]  -> bf16 -------
// Persistent blocks: W staged ONCE per block (bf16, 32 KB LDS); X tile
// row-major f32 [32][132] (pad breaks 8-way bank aliasing). 256 thr,
// 4x4 register tile/thread, f32 accumulate. ~49 KB LDS -> 3 blocks/CU.

__global__ __launch_bounds__(256) void gnn_gemm(const void* Xv, const float* W,
    const float* dis, bf16_t* A, int n, int ntiles, int xfmt) {
  __shared__ bf16_t Ws[128 * 128];  // 32 KB
  __shared__ float Xs[32][132];     // 16.9 KB
  int tid = threadIdx.x;

  // stage W once: f32 global -> bf16 LDS
  for (int i = tid; i < 4096; i += 256) {
    float4 w4 = ((const float4*)W)[i];
    ushort4 o;
    o.x = f2bf(w4.x); o.y = f2bf(w4.y); o.z = f2bf(w4.z); o.w = f2bf(w4.w);
    ((ushort4*)Ws)[i] = o;
  }

  int cx = tid & 31;
  int ry = tid >> 5;
  int r0 = ry * 4;

  for (int t = blockIdx.x; t < ntiles; t += gridDim.x) {
    int rowbase = t * 32;
    __syncthreads();  // Ws ready (1st iter) / prior compute's Xs reads done
    for (int i = tid; i < 1024; i += 256) {
      int r = i >> 5;
      int c = (i & 31) * 4;
      int row = rowbase + r;
      float4 x4 = make_float4(0.0f, 0.0f, 0.0f, 0.0f);
      if (row < n) {
        if (xfmt == 0) {
          x4 = *(const float4*)((const float*)Xv + (size_t)row * 128 + c);
        } else {
          ushort4 v = *(const ushort4*)((const bf16_t*)Xv + (size_t)row * 128 + c);
          x4 = make_float4(bf2f(v.x), bf2f(v.y), bf2f(v.z), bf2f(v.w));
        }
      }
      *(float4*)&Xs[r][c] = x4;
    }
    __syncthreads();

    float acc[4][4];
    for (int a = 0; a < 4; a++)
      for (int b = 0; b < 4; b++) acc[a][b] = 0.0f;

#pragma unroll 4
    for (int k = 0; k < 128; ++k) {
      float x0 = Xs[r0 + 0][k];
      float x1 = Xs[r0 + 1][k];
      float x2 = Xs[r0 + 2][k];
      float x3 = Xs[r0 + 3][k];
      ushort4 wv = *(const ushort4*)&Ws[k * 128 + cx * 4];
      float w0 = bf2f(wv.x), w1 = bf2f(wv.y), w2 = bf2f(wv.z), w3 = bf2f(wv.w);
      acc[0][0] += x0 * w0; acc[0][1] += x0 * w1; acc[0][2] += x0 * w2; acc[0][3] += x0 * w3;
      acc[1][0] += x1 * w0; acc[1][1] += x1 * w1; acc[1][2] += x1 * w2; acc[1][3] += x1 * w3;
      acc[2][0] += x2 * w0; acc[2][1] += x2 * w1; acc[2][2] += x2 * w2; acc[2][3] += x2 * w3;
      acc[3][0] += x3 * w0; acc[3][1] += x3 * w1; acc[3][2] += x3 * w2; acc[3][3] += x3 * w3;
    }

    for (int r = 0; r < 4; r++) {
      int row = rowbase + r0 + r;
      if (row < n) {
        float dd = dis[row];
        ushort4 o;
        o.x = f2bf(acc[r][0] * dd);
        o.y = f2bf(acc[r][1] * dd);
        o.z = f2bf(acc[r][2] * dd);
        o.w = f2bf(acc[r][3] * dd);
        *(ushort4*)(A + (size_t)row * 128 + cx * 4) = o;
      }
    }
  }
}

// --- fused aggregation (+ optional residual+LN+relu) ---
// A holds dis[s]*h[s] (bf16). h_agg[d] = dis[d]*(sum_{s in N(d)} A[s] + A[d]) + bias.
// do_ln: v = h_agg + ori; LN(v)*w+b; relu; write bf16 to Bout.
// else: write f32 h_agg to Fout.

__global__ __launch_bounds__(256) void gnn_aggln(const bf16_t* A,
    const float* dis, const int* row_ptr, const int* csr, const float* bias,
    const float* ori, const float* lnw, const float* lnb,
    bf16_t* Bout, float* Fout, int n, int do_ln) {
  int row = blockIdx.x * 4 + (threadIdx.x >> 6);
  if (row >= n) return;
  int lane = threadIdx.x & 63;
  int e0 = row_ptr[row];
  int e1 = row_ptr[row + 1];
  const ushort2* Av = (const ushort2*)A;
  float ax0 = 0.f, ay0 = 0.f, ax1 = 0.f, ay1 = 0.f;
  float ax2 = 0.f, ay2 = 0.f, ax3 = 0.f, ay3 = 0.f;
  int e = e0;
  for (; e + 3 < e1; e += 4) {  // 4-way unroll: 4 gathers in flight
    int s0 = csr[e], s1 = csr[e + 1], s2 = csr[e + 2], s3 = csr[e + 3];
    ushort2 v0 = Av[(size_t)s0 * 64 + lane];
    ushort2 v1 = Av[(size_t)s1 * 64 + lane];
    ushort2 v2 = Av[(size_t)s2 * 64 + lane];
    ushort2 v3 = Av[(size_t)s3 * 64 + lane];
    ax0 += bf2f(v0.x); ay0 += bf2f(v0.y);
    ax1 += bf2f(v1.x); ay1 += bf2f(v1.y);
    ax2 += bf2f(v2.x); ay2 += bf2f(v2.y);
    ax3 += bf2f(v3.x); ay3 += bf2f(v3.y);
  }
  for (; e < e1; ++e) {
    int s = csr[e];
    ushort2 v = Av[(size_t)s * 64 + lane];
    ax0 += bf2f(v.x); ay0 += bf2f(v.y);
  }
  ushort2 sv = Av[(size_t)row * 64 + lane];  // self-loop term
  float ax = ax0 + ax1 + ax2 + ax3 + bf2f(sv.x);
  float ay = ay0 + ay1 + ay2 + ay3 + bf2f(sv.y);
  float dd = dis[row];
  float2 bb = ((const float2*)bias)[lane];
  float hx = dd * ax + bb.x;
  float hy = dd * ay + bb.y;

  if (do_ln) {
    float2 o2 = ((const float2*)ori)[(size_t)row * 64 + lane];
    float vx = hx + o2.x;
    float vy = hy + o2.y;
    float s = vx + vy;
    float sq = vx * vx + vy * vy;
    for (int off = 32; off >= 1; off >>= 1) {
      s += __shfl_xor(s, off);
      sq += __shfl_xor(sq, off);
    }
    float mu = s * (1.0f / 128.0f);
    float var = sq * (1.0f / 128.0f) - mu * mu;
    float inv = rsqrtf(var + 1e-5f);
    float2 w2 = ((const float2*)lnw)[lane];
    float2 b2 = ((const float2*)lnb)[lane];
    float y0 = (vx - mu) * inv * w2.x + b2.x;
    float y1 = (vy - mu) * inv * w2.y + b2.y;
    if (y0 < 0.0f) y0 = 0.0f;
    if (y1 < 0.0f) y1 = 0.0f;
    ushort2 o;
    o.x = f2bf(y0);
    o.y = f2bf(y1);
    ((ushort2*)Bout)[(size_t)row * 64 + lane] = o;
  } else {
    ((float2*)Fout)[(size_t)row * 64 + lane] = make_float2(hx, hy);
  }
}

// ---------------- driver ----------------

extern "C" void kernel_launch(void* const* d_in, const int* in_sizes, int n_in,
                              void* d_out, int out_size, void* d_ws, size_t ws_size,
                              hipStream_t stream) {
  UnifiedGNN_56521769616171_kernel<<<1, 64, 0, stream>>>();

  // input classification by size (identity under documented dict order)
  int nI = (n_in > 0 && n_in <= 16) ? n_in : 11;
  long best = -1;
  int iFeat = 0;
  for (int i = 0; i < nI; i++)
    if ((long)in_sizes[i] > best) { best = in_sizes[i]; iFeat = i; }
  int iW[2], iV[6], iE[2];
  int nW = 0, nV = 0, nE = 0;
  for (int i = 0; i < nI; i++) {
    if (i == iFeat) continue;
    int s = in_sizes[i];
    if (s == 128 * 128) { if (nW < 2) iW[nW++] = i; }
    else if (s == 128)  { if (nV < 6) iV[nV++] = i; }
    else                { if (nE < 2) iE[nE++] = i; }
  }
  int aFeat = 0, aEs = 1, aEd = 2, aW1 = 3, aB1 = 4, aW2 = 5, aB2 = 6,
      aL1w = 7, aL1b = 8, aL2w = 9, aL2b = 10;
  if (nW == 2 && nV == 6 && nE == 2) {
    aFeat = iFeat;
    aEs = iE[0]; aEd = iE[1];
    aW1 = iW[0]; aW2 = iW[1];
    aB1 = iV[0]; aB2 = iV[1];
    aL1w = iV[2]; aL1b = iV[3]; aL2w = iV[4]; aL2b = iV[5];
  }

  int N = 50000;
  int E = 600000;
  if (in_sizes[aFeat] > 0 && (in_sizes[aFeat] % 128) == 0) N = in_sizes[aFeat] / 128;
  if (in_sizes[aEs] > 0) E = in_sizes[aEs];

  const float* in_feat = (const float*)d_in[aFeat];
  const int*   esrc    = (const int*)d_in[aEs];
  const int*   edst    = (const int*)d_in[aEd];
  const float* W1      = (const float*)d_in[aW1];
  const float* b1      = (const float*)d_in[aB1];
  const float* W2      = (const float*)d_in[aW2];
  const float* b2      = (const float*)d_in[aB2];
  const float* ln1w    = (const float*)d_in[aL1w];
  const float* ln1b    = (const float*)d_in[aL1b];
  const float* ln2w    = (const float*)d_in[aL2w];
  const float* ln2b    = (const float*)d_in[aL2b];

  // workspace carve (~28.6 MB; ws_size >= ~31.2 MB proven in R10/11)
  char* base = (char*)d_ws;
  size_t off = 0;
  int* counts = (int*)(base + off);   off += ((size_t)N * 4 + 255) & ~(size_t)255;
  int* row_ptr = (int*)(base + off);  off += ((size_t)(N + 1) * 4 + 255) & ~(size_t)255;
  int* cursor = (int*)(base + off);   off += ((size_t)N * 4 + 255) & ~(size_t)255;
  int* partials = (int*)(base + off); off += 256;
  int* offsets = (int*)(base + off);  off += 256;
  float* dis = (float*)(base + off);  off += ((size_t)N * 4 + 255) & ~(size_t)255;
  int* csr = (int*)(base + off);      off += ((size_t)E * 4 + 255) & ~(size_t)255;
  bf16_t* A = (bf16_t*)(base + off);  off += ((size_t)N * 256 + 255) & ~(size_t)255;  // gemm out (pre-scaled)
  bf16_t* B = (bf16_t*)(base + off);  off += ((size_t)N * 256 + 255) & ~(size_t)255;  // LN out

  int nb = (N + 1023) / 1024;
  int gN = (N + 255) / 256;
  int gE = (E + 255) / 256;
  int ntiles = (N + 31) / 32;
  int gemm_grid = 768;  // 3 blocks/CU at 49 KB LDS
  int row_grid = (N + 3) / 4;

  gnn_zero<<<gN, 256, 0, stream>>>(counts, N);
  gnn_count<<<gE, 256, 0, stream>>>(edst, counts, E, N);
  gnn_scan1<<<nb, 256, 0, stream>>>(counts, row_ptr, partials, N);
  gnn_scan2<<<1, 64, 0, stream>>>(partials, offsets, nb, row_ptr, N, E);
  gnn_scan3<<<nb, 256, 0, stream>>>(row_ptr, offsets, cursor, counts, dis, N);
  gnn_fill<<<gE, 256, 0, stream>>>(esrc, edst, cursor, csr, E, N);

  // conv1 + LN1(+res,relu):  A = dis*(in_feat@W1);  B = relu(LN1(agg(A)+b1 + ori))
  gnn_gemm<<<gemm_grid, 256, 0, stream>>>(in_feat, W1, dis, A, N, ntiles, 0);
  gnn_aggln<<<row_grid, 256, 0, stream>>>(A, dis, row_ptr, csr, b1, in_feat,
                                          ln1w, ln1b, B, (float*)nullptr, N, 1);

  // conv2 + LN2(+res,relu)
  gnn_gemm<<<gemm_grid, 256, 0, stream>>>(B, W2, dis, A, N, ntiles, 1);
  gnn_aggln<<<row_grid, 256, 0, stream>>>(A, dis, row_ptr, csr, b2, in_feat,
                                          ln2w, ln2b, B, (float*)nullptr, N, 1);

  // conv3 -> final f32 output
  gnn_gemm<<<gemm_grid, 256, 0, stream>>>(B, W2, dis, A, N, ntiles, 1);
  gnn_aggln<<<row_grid, 256, 0, stream>>>(A, dis, row_ptr, csr, b2,
                                          (const float*)nullptr, (const float*)nullptr,
                                          (const float*)nullptr, (bf16_t*)nullptr,
                                          (float*)d_out, N, 0);
}